// Round 9
// baseline (141.610 us; speedup 1.0000x reference)
//
#include <hip/hip_runtime.h>
#include <cmath>

// ---------------------------------------------------------------------------
// MHA forward, bf16-MFMA everywhere.
//   prep (1 kernel): x->bf16 ; W* -> bf16 transposed [n][k] ; RoPE table
//   gemm_qkv (768 blk, XCD m-band swizzled): xb@Wt -> Q/K (RoPE via LDS
//       transpose epilogue, coalesced) / V-transpose epilogue
//   attn: causal flash attn, XCD-partitioned, paired q-chunks, KVBLK=128
//         LDS double-buffered K/V (80 KB dynamic), deferred-max log2 softmax,
//         2x-unrolled tile loop (static buffers), setprio around MFMA
//   gemm_o (256 blk, swizzled): AOb@Wto -> out fp32 (LDS fp32 2-pass epilogue)
// B=2 S=2048 D=1024 H=16 dk=64
// ---------------------------------------------------------------------------

constexpr int Bz = 2, Sq = 2048, Dm = 1024, Hh = 16, DK = 64;
constexpr int Mrows = Bz * Sq;  // 4096

typedef __attribute__((ext_vector_type(4))) float f32x4;
typedef __attribute__((ext_vector_type(2))) __bf16 bf16x2;
typedef __attribute__((ext_vector_type(4))) __bf16 bf16x4;
typedef __attribute__((ext_vector_type(8))) __bf16 bf16x8;
typedef __attribute__((ext_vector_type(8))) short short8v;

__device__ __forceinline__ f32x4 mfma16(bf16x8 a, bf16x8 b, f32x4 c) {
  return __builtin_amdgcn_mfma_f32_16x16x32_bf16(a, b, c, 0, 0, 0);
}
__device__ __forceinline__ short bfb(float x) {
  return __builtin_bit_cast(short, (__bf16)x);
}
// async global->LDS, 16 B per lane; lds ptr must be wave-uniform
__device__ __forceinline__ void gload16(const void* g, void* l) {
  __builtin_amdgcn_global_load_lds(
      (__attribute__((address_space(1))) void*)g,
      (__attribute__((address_space(3))) void*)l, 16, 0, 0);
}

// ============================ prep (fused) =================================
// blocks [0,2048): x->bf16 ; [2048,6144): W transpose ; [6144,6400): RoPE tbl
__global__ __launch_bounds__(256) void prep_kernel(
    const float* __restrict__ x, const float* __restrict__ Wq,
    const float* __restrict__ Wk, const float* __restrict__ Wv,
    const float* __restrict__ Wo, __bf16* __restrict__ xb,
    __bf16* __restrict__ Wt, float2* __restrict__ tbl) {
  __shared__ float tile[32][33];
  const int bid = blockIdx.x, tid = threadIdx.x;
  if (bid < 2048) {
    int t = bid * 256 + tid;
    const float4* p = (const float4*)x + (size_t)t * 2;
    float4 a = p[0], b = p[1];
    bf16x8 o = {(__bf16)a.x, (__bf16)a.y, (__bf16)a.z, (__bf16)a.w,
                (__bf16)b.x, (__bf16)b.y, (__bf16)b.z, (__bf16)b.w};
    *(bf16x8*)(xb + (size_t)t * 8) = o;
  } else if (bid < 6144) {
    int wid = bid - 2048;
    int z = wid >> 10, rem = wid & 1023;
    const float* W = (z == 0) ? Wq : (z == 1) ? Wk : (z == 2) ? Wv : Wo;
    __bf16* out = Wt + (size_t)z * Dm * Dm;
    int r0 = (rem >> 5) * 32, c0 = (rem & 31) * 32;
    int r = tid >> 3, c4 = (tid & 7) * 4;
    float4 v = *(const float4*)&W[(size_t)(r0 + r) * Dm + c0 + c4];
    tile[r][c4] = v.x; tile[r][c4 + 1] = v.y;
    tile[r][c4 + 2] = v.z; tile[r][c4 + 3] = v.w;
    __syncthreads();
    int nl = tid >> 3, k4 = (tid & 7) * 4;
    bf16x4 o = {(__bf16)tile[k4][nl], (__bf16)tile[k4 + 1][nl],
                (__bf16)tile[k4 + 2][nl], (__bf16)tile[k4 + 3][nl]};
    *(bf16x4*)&out[(size_t)(c0 + nl) * Dm + r0 + k4] = o;
  } else {
    int t = (bid - 6144) * 256 + tid;  // 65536
    int s = t >> 5, j = t & 31;
    float inv = exp2f(-13.287712379549449f * (1.0f / 32.0f) * (float)j);
    float sn, cs;
    sincosf((float)s * inv, &sn, &cs);
    tbl[t] = make_float2(cs, sn);
  }
}

// ========================= bf16 MFMA GEMM core =============================
// acc[4][4] = A[m0..+128][:] @ Bt[n0..+128][:]^T, BK=32, 4 waves, 16x16x32.
__device__ __forceinline__ void gemm_core(const __bf16* __restrict__ A,
                                          const __bf16* __restrict__ Bt,
                                          char* smem, f32x4 (&acc)[4][4],
                                          int m0, int n0, int tid) {
  short* As = (short*)smem;            // [128][32]
  short* Bs = (short*)(smem + 8192);   // [128][32]
  const int lane = tid & 63, w = tid >> 6;
  const int qi = lane & 15, c = lane >> 4;
  const int wr = w >> 1, wc = w & 1;
  const int srow = lane >> 2, scol = (lane & 3) * 8;
  const __bf16* gA = A + (size_t)(m0 + w * 16 + srow) * Dm + scol;
  const __bf16* gB = Bt + (size_t)(n0 + w * 16 + srow) * Dm + scol;
  short* lA = As + w * 512;  // wave-uniform LDS dest
  short* lB = Bs + w * 512;

#pragma unroll
  for (int i = 0; i < 4; ++i)
#pragma unroll
    for (int j = 0; j < 4; ++j) acc[i][j] = (f32x4){0.f, 0.f, 0.f, 0.f};

  for (int k0 = 0; k0 < Dm; k0 += 32) {
    if (k0) __syncthreads();
    gload16(gA + k0, lA);
    gload16(gA + (size_t)64 * Dm + k0, lA + 2048);
    gload16(gB + k0, lB);
    gload16(gB + (size_t)64 * Dm + k0, lB + 2048);
    __syncthreads();
    bf16x8 af[4], bfv[4];
#pragma unroll
    for (int i = 0; i < 4; ++i) {
      af[i]  = *(bf16x8*)(As + (wr * 64 + i * 16 + qi) * 32 + c * 8);
      bfv[i] = *(bf16x8*)(Bs + (wc * 64 + i * 16 + qi) * 32 + c * 8);
    }
#pragma unroll
    for (int i = 0; i < 4; ++i)
#pragma unroll
      for (int j = 0; j < 4; ++j) acc[i][j] = mfma16(af[i], bfv[j], acc[i][j]);
  }
}

// ===================== fused QKV GEMM (flattened grid) =====================
// 768 blocks. XCD m-band swizzle: xcd=bid&7 owns m-blocks 4*xcd..+3; within
// XCD order is m-inner so B tiles get back-to-back L2 reuse.
// z==0: Q + RoPE (scaled 0.125*log2e). z==1: K + RoPE. z==2: Vt[bh][d][s].
__global__ __launch_bounds__(256) void gemm_qkv(
    const __bf16* __restrict__ xb, const __bf16* __restrict__ Wt,
    const float2* __restrict__ tbl, __bf16* __restrict__ Qb,
    __bf16* __restrict__ Kb, __bf16* __restrict__ Vt) {
  __shared__ __align__(16) char smem[34816];
  const int tid = threadIdx.x;
  const int bid = blockIdx.x;
  const int xcd = bid & 7, r8 = bid >> 3;          // r8 in [0,96)
  const int mb = (xcd << 2) | (r8 & 3);            // m-block 0..31
  const int zn = r8 >> 2;                          // 0..23
  const int z = zn >> 3, nb = zn & 7;
  const int m0 = mb * 128, n0 = nb * 128;

  f32x4 acc[4][4];
  gemm_core(xb, Wt + (size_t)z * Dm * Dm, smem, acc, m0, n0, tid);

  const int lane = tid & 63, w = tid >> 6;
  const int qi = lane & 15, c = lane >> 4;
  const int wr = w >> 1, wc = w & 1;

  if (z == 2) {  // Vt[bh][d][s]
    __syncthreads();
    short* T = (short*)smem;  // [128][136] padded
#pragma unroll
    for (int i = 0; i < 4; ++i)
#pragma unroll
      for (int j = 0; j < 4; ++j) {
        int nl = wc * 64 + j * 16 + qi;
        int mbr = wr * 64 + i * 16 + c * 4;
        bf16x4 pk = {(__bf16)acc[i][j][0], (__bf16)acc[i][j][1],
                     (__bf16)acc[i][j][2], (__bf16)acc[i][j][3]};
        *(bf16x4*)(T + nl * 136 + mbr) = pk;
      }
    __syncthreads();
    short* C = (short*)Vt;
    int b = m0 >> 11, sb = m0 & (Sq - 1);
#pragma unroll
    for (int it = 0; it < 8; ++it) {
      int f = tid + it * 256;
      int nl = f >> 4, mc = f & 15;
      short8v v = *(short8v*)(T + nl * 136 + mc * 8);
      int ng = n0 + nl;
      int d = ng & (DK - 1), h = (ng >> 6) & (Hh - 1);
      *(short8v*)(C + ((size_t)(b * Hh + h) * DK + d) * Sq + sb + mc * 8) = v;
    }
  } else {  // Q or K: stage raw bf16, RoPE on re-read (pairs in-thread)
    __syncthreads();
    short* T = (short*)smem;  // [128][136]
#pragma unroll
    for (int i = 0; i < 4; ++i)
#pragma unroll
      for (int j = 0; j < 4; ++j) {
        int nl = wc * 64 + j * 16 + qi;
        int mbr = wr * 64 + i * 16 + c * 4;
#pragma unroll
        for (int rr = 0; rr < 4; ++rr)
          T[(mbr + rr) * 136 + nl] = bfb(acc[i][j][rr]);
      }
    __syncthreads();
    const float sc = (z == 0) ? 0.18033688011112042f : 1.0f;  // 0.125*log2e
    short* C = (short*)((z == 0) ? Qb : Kb);
    const int b = m0 >> 11;
#pragma unroll
    for (int it = 0; it < 8; ++it) {
      int f = tid + it * 256;
      int ml = f >> 4, c16 = f & 15;
      bf16x8 v = *(bf16x8*)(T + ml * 136 + c16 * 8);
      int s = (m0 + ml) & (Sq - 1);
      int n = n0 + c16 * 8;
      int d0 = n & (DK - 1), h = (n >> 6) & (Hh - 1);
      int jj = d0 >> 1;
      float4 t01 = *(const float4*)&tbl[s * 32 + jj];      // cos0,sin0,cos1,sin1
      float4 t23 = *(const float4*)&tbl[s * 32 + jj + 2];
      bf16x8 o;
      float x0 = (float)v[0], y0 = (float)v[1];
      o[0] = (__bf16)((x0 * t01.x - y0 * t01.y) * sc);
      o[1] = (__bf16)((y0 * t01.x + x0 * t01.y) * sc);
      float x1 = (float)v[2], y1 = (float)v[3];
      o[2] = (__bf16)((x1 * t01.z - y1 * t01.w) * sc);
      o[3] = (__bf16)((y1 * t01.z + x1 * t01.w) * sc);
      float x2 = (float)v[4], y2 = (float)v[5];
      o[4] = (__bf16)((x2 * t23.x - y2 * t23.y) * sc);
      o[5] = (__bf16)((y2 * t23.x + x2 * t23.y) * sc);
      float x3 = (float)v[6], y3 = (float)v[7];
      o[6] = (__bf16)((x3 * t23.z - y3 * t23.w) * sc);
      o[7] = (__bf16)((y3 * t23.z + x3 * t23.w) * sc);
      *(bf16x8*)(C + ((size_t)(b * Hh + h) * Sq + s) * DK + d0) = o;
    }
  }
}

// ============================== O GEMM =====================================
// 256 blocks, XCD m-band swizzle. fp32 output via 2-pass LDS transpose.
__global__ __launch_bounds__(256) void gemm_o(
    const __bf16* __restrict__ AOb, const __bf16* __restrict__ Wto,
    float* __restrict__ C) {
  __shared__ __align__(16) char smem[34816];
  const int tid = threadIdx.x;
  const int bid = blockIdx.x;
  const int xcd = bid & 7, r8 = bid >> 3;          // r8 in [0,32)
  const int mb = (xcd << 2) | (r8 & 3);
  const int nb = r8 >> 2;
  const int m0 = mb * 128, n0 = nb * 128;

  f32x4 acc[4][4];
  gemm_core(AOb, Wto, smem, acc, m0, n0, tid);

  const int lane = tid & 63, w = tid >> 6;
  const int qi = lane & 15, c = lane >> 4;
  const int wr = w >> 1, wc = w & 1;
  float* T32 = (float*)smem;  // [64][132] = 33792 B

#pragma unroll
  for (int pass = 0; pass < 2; ++pass) {
    __syncthreads();
#pragma unroll
    for (int i2 = 0; i2 < 2; ++i2) {
      int i = pass * 2 + i2;
#pragma unroll
      for (int j = 0; j < 4; ++j) {
        int nl = wc * 64 + j * 16 + qi;
        int cm = wr * 32 + i2 * 16 + c * 4;
#pragma unroll
        for (int rr = 0; rr < 4; ++rr)
          T32[(cm + rr) * 132 + nl] = acc[i][j][rr];
      }
    }
    __syncthreads();
#pragma unroll
    for (int it = 0; it < 8; ++it) {
      int f = tid + it * 256;           // 0..2047
      int cm = f >> 5, c4 = f & 31;
      float4 v = *(float4*)(T32 + cm * 132 + c4 * 4);
      int m = m0 + (cm >> 5) * 64 + pass * 32 + (cm & 31);
      *(float4*)&C[(size_t)m * Dm + n0 + c4 * 4] = v;
    }
  }
}

// ======================= Flash attention (bf16 MFMA) ========================
// 512 blocks x 4 waves, KVBLK=128. Block -> (bh, paired q-chunks): uniform
// 17 k-tiles per block. XCD-partitioned (bid&7 -> 4 heads). K/V LDS double-
// buffer (dynamic 80 KB) via swizzled-source global_load_lds; 2x-unrolled
// loop (static buffer bases); deferred-max softmax (log2 domain, Q-folded).
// LDS map: K[2][16384] @0 ; V[2][16384] @32768 ; P[4][4096] @65536.
__global__ __launch_bounds__(256) void attn_kernel(
    const __bf16* __restrict__ Qb, const __bf16* __restrict__ Kb,
    const __bf16* __restrict__ Vt, __bf16* __restrict__ AOb) {
  extern __shared__ __align__(16) char smem[];

  const int bid = blockIdx.x;            // 512
  const int xcd = bid & 7;               // hw round-robin -> XCD id (heuristic)
  const int idx = bid >> 3;              // 0..63 within XCD
  const int bh = (xcd << 2) | (idx >> 4);
  const int pair = idx & 15;             // chunks: 31-pair then pair
  const int b = bh >> 4, h = bh & (Hh - 1);
  const int tid = threadIdx.x, lane = tid & 63, wave = tid >> 6;
  const int g = lane >> 4, qi = lane & 15;

  const __bf16* Qp = Qb + (size_t)bh * Sq * DK;
  const __bf16* Kp = Kb + (size_t)bh * Sq * DK;
  const __bf16* Vp = Vt + (size_t)bh * DK * Sq;

  char* myP = smem + 65536 + wave * 4096;  // [16 q rows][256 B]

  // staging lane geometry
  const int srow8 = lane >> 3, scol8 = lane & 7;     // K: 8 rows/seg, 128B rows
  const int srow4 = lane >> 4, scol16v = lane & 15;  // V: 4 rows/seg, 256B rows
  short* AOs = (short*)AOb;

  // stage K[128][64] + V[64][128] tile kt into buffer cb (source-swizzled)
  auto stage = [&](int cb, int kt) {
    const int kbase = kt * 128;
    char* Kd = smem + cb * 16384;
    char* Vd = smem + 32768 + cb * 16384;
#pragma unroll
    for (int s = 0; s < 4; ++s) {
      int seg = wave * 4 + s;
      int r = seg * 8 + srow8;                         // K row 0..127
      gload16(Kp + (size_t)(kbase + r) * DK + ((scol8 ^ (r & 7)) << 3),
              Kd + seg * 1024);
      int d = seg * 4 + srow4;                         // V row 0..63
      gload16(Vp + (size_t)d * Sq + kbase + ((scol16v ^ (d & 15)) << 3),
              Vd + seg * 1024);
    }
  };

  // one 128-k tile
  auto tile = [&](const char* Kt, const char* Vv, int kt, int qc, int q0w,
                  const bf16x8& qf0, const bf16x8& qf1, f32x4 (&acc)[4],
                  float& m_, float& l_) {
    const int kbase = kt * 128;

    // ---- QK^T: S^T[k=128][q=16] ----
    f32x4 st[8];
    __builtin_amdgcn_s_setprio(1);
#pragma unroll
    for (int bb = 0; bb < 8; ++bb) {
      int rr = 16 * bb + qi;
      bf16x8 k0 = *(const bf16x8*)(Kt + rr * 128 + ((g ^ (rr & 7)) << 4));
      bf16x8 k1 = *(const bf16x8*)(Kt + rr * 128 + (((g + 4) ^ (rr & 7)) << 4));
      st[bb] = mfma16(k0, qf0, (f32x4){0.f, 0.f, 0.f, 0.f});
      st[bb] = mfma16(k1, qf1, st[bb]);
    }
    __builtin_amdgcn_s_setprio(0);

    // ---- V fragments (latency hides under softmax) ----
    bf16x8 vf[4][4];
#pragma unroll
    for (int j = 0; j < 4; ++j) {
      int rowb = (16 * j + qi) * 256;
#pragma unroll
      for (int cc = 0; cc < 4; ++cc)
        vf[j][cc] = *(const bf16x8*)(Vv + rowb + (((4 * cc + g) ^ qi) << 4));
    }

    // ---- mask (diagonal tile only) + tree max ----
    if (kt == (qc >> 1)) {
#pragma unroll
      for (int bb = 0; bb < 8; ++bb)
#pragma unroll
        for (int r = 0; r < 4; ++r)
          if (kbase + 16 * bb + 4 * g + r > q0w + qi) st[bb][r] = -1e30f;
    }
    float mb[8];
#pragma unroll
    for (int bb = 0; bb < 8; ++bb)
      mb[bb] = fmaxf(fmaxf(st[bb][0], st[bb][1]), fmaxf(st[bb][2], st[bb][3]));
    float tmax = fmaxf(fmaxf(fmaxf(mb[0], mb[1]), fmaxf(mb[2], mb[3])),
                       fmaxf(fmaxf(mb[4], mb[5]), fmaxf(mb[6], mb[7])));
    tmax = fmaxf(tmax, __shfl_xor(tmax, 16));
    tmax = fmaxf(tmax, __shfl_xor(tmax, 32));

    // deferred-max: rescale only when the running max grew by > 7 (log2)
    if (!__all(tmax <= m_ + 7.0f)) {
      const float mnew = fmaxf(m_, tmax);
      const float corr = exp2f(m_ - mnew);
      l_ *= corr;
      float cr[4];
#pragma unroll
      for (int r = 0; r < 4; ++r) cr[r] = __shfl(corr, 4 * g + r);
#pragma unroll
      for (int j = 0; j < 4; ++j) {
        acc[j][0] *= cr[0]; acc[j][1] *= cr[1];
        acc[j][2] *= cr[2]; acc[j][3] *= cr[3];
      }
      m_ = mnew;
    }

    // ---- exp2, pack, P -> LDS (swizzled, conflict-free) ----
    float lsb[8];
#pragma unroll
    for (int bb = 0; bb < 8; ++bb) {
      float p0 = exp2f(st[bb][0] - m_), p1 = exp2f(st[bb][1] - m_);
      float p2 = exp2f(st[bb][2] - m_), p3 = exp2f(st[bb][3] - m_);
      lsb[bb] = (p0 + p1) + (p2 + p3);
      bf16x2 w0 = {(__bf16)p0, (__bf16)p1};
      bf16x2 w1 = {(__bf16)p2, (__bf16)p3};
      *(uint2*)(myP + qi * 256 + ((((2 * bb + (g >> 1)) ^ qi) << 4) |
                                  ((g & 1) << 3))) =
          make_uint2(__builtin_bit_cast(unsigned int, w0),
                     __builtin_bit_cast(unsigned int, w1));
    }
    float ls = ((lsb[0] + lsb[1]) + (lsb[2] + lsb[3])) +
               ((lsb[4] + lsb[5]) + (lsb[6] + lsb[7]));
    ls += __shfl_xor(ls, 16);
    ls += __shfl_xor(ls, 32);
    l_ += ls;

    // ---- PV ----
    bf16x8 pa[4];
#pragma unroll
    for (int cc = 0; cc < 4; ++cc)
      pa[cc] = *(const bf16x8*)(myP + qi * 256 + (((g + 4 * cc) ^ qi) << 4));
    __builtin_amdgcn_s_setprio(1);
#pragma unroll
    for (int j = 0; j < 4; ++j)
#pragma unroll
      for (int cc = 0; cc < 4; ++cc)
        acc[j] = mfma16(pa[cc], vf[j][cc], acc[j]);
    __builtin_amdgcn_s_setprio(0);
  };

  auto run_chunk = [&](int qc) {
    const int q0w = qc * 64 + wave * 16;
    const int nt = (qc >> 1) + 1;  // 128-k tiles

    const bf16x8 qf0 = *(const bf16x8*)(Qp + (q0w + qi) * DK + 8 * g);
    const bf16x8 qf1 = *(const bf16x8*)(Qp + (q0w + qi) * DK + 32 + 8 * g);

    f32x4 acc[4];
#pragma unroll
    for (int j = 0; j < 4; ++j) acc[j] = (f32x4){0.f, 0.f, 0.f, 0.f};
    float m_ = -1e30f, l_ = 0.f;

    __syncthreads();  // protect buffers from previous chunk's readers
    stage(0, 0);

    int kt = 0;
    for (; kt + 1 < nt; kt += 2) {
      __syncthreads();                 // buf0 staged
      stage(1, kt + 1);
      tile(smem, smem + 32768, kt, qc, q0w, qf0, qf1, acc, m_, l_);
      __syncthreads();                 // buf1 staged
      if (kt + 2 < nt) stage(0, kt + 2);
      tile(smem + 16384, smem + 49152, kt + 1, qc, q0w, qf0, qf1, acc, m_, l_);
    }
    if (kt < nt) {
      __syncthreads();
      tile(smem, smem + 32768, kt, qc, q0w, qf0, qf1, acc, m_, l_);
    }

    const float inv = 1.f / l_;
    float ir[4];
#pragma unroll
    for (int r = 0; r < 4; ++r) ir[r] = __shfl(inv, 4 * g + r);
#pragma unroll
    for (int j = 0; j < 4; ++j)
#pragma unroll
      for (int r = 0; r < 4; ++r)
        AOs[((size_t)b * Sq + q0w + 4 * g + r) * Dm + h * DK + 16 * j + qi] =
            bfb(acc[j][r] * ir[r]);
  };

  run_chunk(31 - pair);  // big chunk first
  run_chunk(pair);
}

// ================================ launch ===================================
extern "C" void kernel_launch(void* const* d_in, const int* in_sizes, int n_in,
                              void* d_out, int out_size, void* d_ws,
                              size_t ws_size, hipStream_t stream) {
  const float* x  = (const float*)d_in[0];
  const float* Wq = (const float*)d_in[1];
  const float* Wk = (const float*)d_in[2];
  const float* Wv = (const float*)d_in[3];
  const float* Wo = (const float*)d_in[4];
  float* out = (float*)d_out;

  char* w = (char*)d_ws;
  __bf16* Qb  = (__bf16*)(w);                 // 8 MB [bh][s][64] (pre-scaled)
  __bf16* Kb  = (__bf16*)(w + (8u << 20));    // 8 MB
  __bf16* Vt  = (__bf16*)(w + (16u << 20));   // 8 MB [bh][64][s]
  __bf16* AOb = (__bf16*)(w + (24u << 20));   // 8 MB [B,S,D]
  __bf16* xb  = (__bf16*)(w + (32u << 20));   // 8 MB [4096][1024]
  __bf16* Wt  = (__bf16*)(w + (40u << 20));   // 4 x 2 MB [n][k]
  float2* tbl = (float2*)(w + (48u << 20));   // 512 KB

  prep_kernel<<<6400, 256, 0, stream>>>(x, Wq, Wk, Wv, Wo, xb, Wt, tbl);
  gemm_qkv<<<768, 256, 0, stream>>>(xb, Wt, tbl, Qb, Kb, Vt);
  attn_kernel<<<512, 256, 81920, stream>>>(Qb, Kb, Vt, AOb);
  gemm_o<<<256, 256, 0, stream>>>(AOb, Wt + (size_t)3 * Dm * Dm, out);
}

// Round 10
// 127.503 us; speedup vs baseline: 1.1106x; 1.1106x over previous
//
#include <hip/hip_runtime.h>
#include <cmath>

// ---------------------------------------------------------------------------
// MHA forward, bf16-MFMA everywhere.
//   prep (1 kernel): x->bf16 ; W* -> bf16 transposed [n][k] ; RoPE table
//   gemm_qkv (768 blk, XCD m-band swizzled): xb@Wt -> Q/K (RoPE via LDS
//       transpose epilogue, coalesced) / V-transpose epilogue
//   attn: causal flash attn, KVBLK=64, 8-wave blocks with k-parity split
//         (two waves per q-row-group alternate k-tiles, shared K/V staging,
//         exact softmax-state merge), XCD-partitioned, paired q-chunks,
//         deferred-max log2 softmax
//   gemm_o (256 blk, swizzled): AOb@Wto -> out fp32 (LDS fp32 2-pass epilogue)
// B=2 S=2048 D=1024 H=16 dk=64
// ---------------------------------------------------------------------------

constexpr int Bz = 2, Sq = 2048, Dm = 1024, Hh = 16, DK = 64;
constexpr int Mrows = Bz * Sq;  // 4096

typedef __attribute__((ext_vector_type(4))) float f32x4;
typedef __attribute__((ext_vector_type(2))) __bf16 bf16x2;
typedef __attribute__((ext_vector_type(4))) __bf16 bf16x4;
typedef __attribute__((ext_vector_type(8))) __bf16 bf16x8;
typedef __attribute__((ext_vector_type(8))) short short8v;

__device__ __forceinline__ f32x4 mfma16(bf16x8 a, bf16x8 b, f32x4 c) {
  return __builtin_amdgcn_mfma_f32_16x16x32_bf16(a, b, c, 0, 0, 0);
}
__device__ __forceinline__ short bfb(float x) {
  return __builtin_bit_cast(short, (__bf16)x);
}
// async global->LDS, 16 B per lane; lds ptr must be wave-uniform
__device__ __forceinline__ void gload16(const void* g, void* l) {
  __builtin_amdgcn_global_load_lds(
      (__attribute__((address_space(1))) void*)g,
      (__attribute__((address_space(3))) void*)l, 16, 0, 0);
}

// ============================ prep (fused) =================================
// blocks [0,2048): x->bf16 ; [2048,6144): W transpose ; [6144,6400): RoPE tbl
__global__ __launch_bounds__(256) void prep_kernel(
    const float* __restrict__ x, const float* __restrict__ Wq,
    const float* __restrict__ Wk, const float* __restrict__ Wv,
    const float* __restrict__ Wo, __bf16* __restrict__ xb,
    __bf16* __restrict__ Wt, float2* __restrict__ tbl) {
  __shared__ float tile[32][33];
  const int bid = blockIdx.x, tid = threadIdx.x;
  if (bid < 2048) {
    int t = bid * 256 + tid;
    const float4* p = (const float4*)x + (size_t)t * 2;
    float4 a = p[0], b = p[1];
    bf16x8 o = {(__bf16)a.x, (__bf16)a.y, (__bf16)a.z, (__bf16)a.w,
                (__bf16)b.x, (__bf16)b.y, (__bf16)b.z, (__bf16)b.w};
    *(bf16x8*)(xb + (size_t)t * 8) = o;
  } else if (bid < 6144) {
    int wid = bid - 2048;
    int z = wid >> 10, rem = wid & 1023;
    const float* W = (z == 0) ? Wq : (z == 1) ? Wk : (z == 2) ? Wv : Wo;
    __bf16* out = Wt + (size_t)z * Dm * Dm;
    int r0 = (rem >> 5) * 32, c0 = (rem & 31) * 32;
    int r = tid >> 3, c4 = (tid & 7) * 4;
    float4 v = *(const float4*)&W[(size_t)(r0 + r) * Dm + c0 + c4];
    tile[r][c4] = v.x; tile[r][c4 + 1] = v.y;
    tile[r][c4 + 2] = v.z; tile[r][c4 + 3] = v.w;
    __syncthreads();
    int nl = tid >> 3, k4 = (tid & 7) * 4;
    bf16x4 o = {(__bf16)tile[k4][nl], (__bf16)tile[k4 + 1][nl],
                (__bf16)tile[k4 + 2][nl], (__bf16)tile[k4 + 3][nl]};
    *(bf16x4*)&out[(size_t)(c0 + nl) * Dm + r0 + k4] = o;
  } else {
    int t = (bid - 6144) * 256 + tid;  // 65536
    int s = t >> 5, j = t & 31;
    float inv = exp2f(-13.287712379549449f * (1.0f / 32.0f) * (float)j);
    float sn, cs;
    sincosf((float)s * inv, &sn, &cs);
    tbl[t] = make_float2(cs, sn);
  }
}

// ========================= bf16 MFMA GEMM core =============================
// acc[4][4] = A[m0..+128][:] @ Bt[n0..+128][:]^T, BK=32, 4 waves, 16x16x32.
__device__ __forceinline__ void gemm_core(const __bf16* __restrict__ A,
                                          const __bf16* __restrict__ Bt,
                                          char* smem, f32x4 (&acc)[4][4],
                                          int m0, int n0, int tid) {
  short* As = (short*)smem;            // [128][32]
  short* Bs = (short*)(smem + 8192);   // [128][32]
  const int lane = tid & 63, w = tid >> 6;
  const int qi = lane & 15, c = lane >> 4;
  const int wr = w >> 1, wc = w & 1;
  const int srow = lane >> 2, scol = (lane & 3) * 8;
  const __bf16* gA = A + (size_t)(m0 + w * 16 + srow) * Dm + scol;
  const __bf16* gB = Bt + (size_t)(n0 + w * 16 + srow) * Dm + scol;
  short* lA = As + w * 512;  // wave-uniform LDS dest
  short* lB = Bs + w * 512;

#pragma unroll
  for (int i = 0; i < 4; ++i)
#pragma unroll
    for (int j = 0; j < 4; ++j) acc[i][j] = (f32x4){0.f, 0.f, 0.f, 0.f};

  for (int k0 = 0; k0 < Dm; k0 += 32) {
    if (k0) __syncthreads();
    gload16(gA + k0, lA);
    gload16(gA + (size_t)64 * Dm + k0, lA + 2048);
    gload16(gB + k0, lB);
    gload16(gB + (size_t)64 * Dm + k0, lB + 2048);
    __syncthreads();
    bf16x8 af[4], bfv[4];
#pragma unroll
    for (int i = 0; i < 4; ++i) {
      af[i]  = *(bf16x8*)(As + (wr * 64 + i * 16 + qi) * 32 + c * 8);
      bfv[i] = *(bf16x8*)(Bs + (wc * 64 + i * 16 + qi) * 32 + c * 8);
    }
#pragma unroll
    for (int i = 0; i < 4; ++i)
#pragma unroll
      for (int j = 0; j < 4; ++j) acc[i][j] = mfma16(af[i], bfv[j], acc[i][j]);
  }
}

// ===================== fused QKV GEMM (flattened grid) =====================
// 768 blocks. XCD m-band swizzle: xcd=bid&7 owns m-blocks 4*xcd..+3; within
// XCD order is m-inner so B tiles get back-to-back L2 reuse.
// z==0: Q + RoPE (scaled 0.125*log2e). z==1: K + RoPE. z==2: Vt[bh][d][s].
__global__ __launch_bounds__(256) void gemm_qkv(
    const __bf16* __restrict__ xb, const __bf16* __restrict__ Wt,
    const float2* __restrict__ tbl, __bf16* __restrict__ Qb,
    __bf16* __restrict__ Kb, __bf16* __restrict__ Vt) {
  __shared__ __align__(16) char smem[34816];
  const int tid = threadIdx.x;
  const int bid = blockIdx.x;
  const int xcd = bid & 7, r8 = bid >> 3;          // r8 in [0,96)
  const int mb = (xcd << 2) | (r8 & 3);            // m-block 0..31
  const int zn = r8 >> 2;                          // 0..23
  const int z = zn >> 3, nb = zn & 7;
  const int m0 = mb * 128, n0 = nb * 128;

  f32x4 acc[4][4];
  gemm_core(xb, Wt + (size_t)z * Dm * Dm, smem, acc, m0, n0, tid);

  const int lane = tid & 63, w = tid >> 6;
  const int qi = lane & 15, c = lane >> 4;
  const int wr = w >> 1, wc = w & 1;

  if (z == 2) {  // Vt[bh][d][s]
    __syncthreads();
    short* T = (short*)smem;  // [128][136] padded
#pragma unroll
    for (int i = 0; i < 4; ++i)
#pragma unroll
      for (int j = 0; j < 4; ++j) {
        int nl = wc * 64 + j * 16 + qi;
        int mbr = wr * 64 + i * 16 + c * 4;
        bf16x4 pk = {(__bf16)acc[i][j][0], (__bf16)acc[i][j][1],
                     (__bf16)acc[i][j][2], (__bf16)acc[i][j][3]};
        *(bf16x4*)(T + nl * 136 + mbr) = pk;
      }
    __syncthreads();
    short* C = (short*)Vt;
    int b = m0 >> 11, sb = m0 & (Sq - 1);
#pragma unroll
    for (int it = 0; it < 8; ++it) {
      int f = tid + it * 256;
      int nl = f >> 4, mc = f & 15;
      short8v v = *(short8v*)(T + nl * 136 + mc * 8);
      int ng = n0 + nl;
      int d = ng & (DK - 1), h = (ng >> 6) & (Hh - 1);
      *(short8v*)(C + ((size_t)(b * Hh + h) * DK + d) * Sq + sb + mc * 8) = v;
    }
  } else {  // Q or K: stage raw bf16, RoPE on re-read (pairs in-thread)
    __syncthreads();
    short* T = (short*)smem;  // [128][136]
#pragma unroll
    for (int i = 0; i < 4; ++i)
#pragma unroll
      for (int j = 0; j < 4; ++j) {
        int nl = wc * 64 + j * 16 + qi;
        int mbr = wr * 64 + i * 16 + c * 4;
#pragma unroll
        for (int rr = 0; rr < 4; ++rr)
          T[(mbr + rr) * 136 + nl] = bfb(acc[i][j][rr]);
      }
    __syncthreads();
    const float sc = (z == 0) ? 0.18033688011112042f : 1.0f;  // 0.125*log2e
    short* C = (short*)((z == 0) ? Qb : Kb);
    const int b = m0 >> 11;
#pragma unroll
    for (int it = 0; it < 8; ++it) {
      int f = tid + it * 256;
      int ml = f >> 4, c16 = f & 15;
      bf16x8 v = *(bf16x8*)(T + ml * 136 + c16 * 8);
      int s = (m0 + ml) & (Sq - 1);
      int n = n0 + c16 * 8;
      int d0 = n & (DK - 1), h = (n >> 6) & (Hh - 1);
      int jj = d0 >> 1;
      float4 t01 = *(const float4*)&tbl[s * 32 + jj];      // cos0,sin0,cos1,sin1
      float4 t23 = *(const float4*)&tbl[s * 32 + jj + 2];
      bf16x8 o;
      float x0 = (float)v[0], y0 = (float)v[1];
      o[0] = (__bf16)((x0 * t01.x - y0 * t01.y) * sc);
      o[1] = (__bf16)((y0 * t01.x + x0 * t01.y) * sc);
      float x1 = (float)v[2], y1 = (float)v[3];
      o[2] = (__bf16)((x1 * t01.z - y1 * t01.w) * sc);
      o[3] = (__bf16)((y1 * t01.z + x1 * t01.w) * sc);
      float x2 = (float)v[4], y2 = (float)v[5];
      o[4] = (__bf16)((x2 * t23.x - y2 * t23.y) * sc);
      o[5] = (__bf16)((y2 * t23.x + x2 * t23.y) * sc);
      float x3 = (float)v[6], y3 = (float)v[7];
      o[6] = (__bf16)((x3 * t23.z - y3 * t23.w) * sc);
      o[7] = (__bf16)((y3 * t23.z + x3 * t23.w) * sc);
      *(bf16x8*)(C + ((size_t)(b * Hh + h) * Sq + s) * DK + d0) = o;
    }
  }
}

// ============================== O GEMM =====================================
// 256 blocks, XCD m-band swizzle. fp32 output via 2-pass LDS transpose.
__global__ __launch_bounds__(256) void gemm_o(
    const __bf16* __restrict__ AOb, const __bf16* __restrict__ Wto,
    float* __restrict__ C) {
  __shared__ __align__(16) char smem[34816];
  const int tid = threadIdx.x;
  const int bid = blockIdx.x;
  const int xcd = bid & 7, r8 = bid >> 3;          // r8 in [0,32)
  const int mb = (xcd << 2) | (r8 & 3);
  const int nb = r8 >> 2;
  const int m0 = mb * 128, n0 = nb * 128;

  f32x4 acc[4][4];
  gemm_core(AOb, Wto, smem, acc, m0, n0, tid);

  const int lane = tid & 63, w = tid >> 6;
  const int qi = lane & 15, c = lane >> 4;
  const int wr = w >> 1, wc = w & 1;
  float* T32 = (float*)smem;  // [64][132] = 33792 B

#pragma unroll
  for (int pass = 0; pass < 2; ++pass) {
    __syncthreads();
#pragma unroll
    for (int i2 = 0; i2 < 2; ++i2) {
      int i = pass * 2 + i2;
#pragma unroll
      for (int j = 0; j < 4; ++j) {
        int nl = wc * 64 + j * 16 + qi;
        int cm = wr * 32 + i2 * 16 + c * 4;
#pragma unroll
        for (int rr = 0; rr < 4; ++rr)
          T32[(cm + rr) * 132 + nl] = acc[i][j][rr];
      }
    }
    __syncthreads();
#pragma unroll
    for (int it = 0; it < 8; ++it) {
      int f = tid + it * 256;           // 0..2047
      int cm = f >> 5, c4 = f & 31;
      float4 v = *(float4*)(T32 + cm * 132 + c4 * 4);
      int m = m0 + (cm >> 5) * 64 + pass * 32 + (cm & 31);
      *(float4*)&C[(size_t)m * Dm + n0 + c4 * 4] = v;
    }
  }
}

// ======================= Flash attention (bf16 MFMA) ========================
// 512 blocks x 8 waves (512 thr), KVBLK=64. wave -> (rg = row-group 0..3,
// par = k-parity). Waves par=0/1 process the SAME 64-row q-chunk on
// alternating 64-k tiles sharing one LDS K/V staging; exact softmax-state
// merge at chunk end. Paired q-chunks (uniform 33 tiles). XCD-partitioned.
// LDS: K[2][8KB]@0, V[2][8KB]@16K, P[8][2KB]@32K = 48 KB -> 2 blocks/CU.
__global__ __launch_bounds__(512, 4) void attn_kernel(
    const __bf16* __restrict__ Qb, const __bf16* __restrict__ Kb,
    const __bf16* __restrict__ Vt, __bf16* __restrict__ AOb) {
  __shared__ __align__(16) char smem[49152];

  const int bid = blockIdx.x;            // 512
  const int xcd = bid & 7;               // hw round-robin -> XCD id (heuristic)
  const int idx = bid >> 3;              // 0..63 within XCD
  const int bh = (xcd << 2) | (idx >> 4);
  const int pair = idx & 15;             // chunks: 31-pair then pair
  const int b = bh >> 4, h = bh & (Hh - 1);
  const int tid = threadIdx.x, lane = tid & 63, w = tid >> 6;  // w 0..7
  const int rg = w & 3, par = w >> 2;
  const int g = lane >> 4, qi = lane & 15;

  const __bf16* Qp = Qb + (size_t)bh * Sq * DK;
  const __bf16* Kp = Kb + (size_t)bh * Sq * DK;
  const __bf16* Vp = Vt + (size_t)bh * DK * Sq;

  char* myP = smem + 32768 + w * 2048;
  const int swz = (qi & 7) << 4;
  const int srow8 = lane >> 3, scol8 = lane & 7;
  short* AOs = (short*)AOb;

  // stage K[64][64] + V[64][64-col window] tile kt into buffer cb.
  // 8 waves x (1 K-seg + 1 V-seg of 1KB each); source pre-swizzled.
  auto stage = [&](int cb, int kt) {
    const int kbase = kt * 64;
    char* Kd = smem + cb * 8192;
    char* Vd = smem + 16384 + cb * 8192;
    int r = w * 8 + srow8;                         // 0..63
    int csrc = (scol8 ^ (r & 7)) << 3;             // swizzled source col (elems)
    gload16(Kp + (size_t)(kbase + r) * DK + csrc, Kd + w * 1024);
    gload16(Vp + (size_t)r * Sq + kbase + csrc, Vd + w * 1024);
  };

  // one 64-k tile (round-8 body)
  auto tile = [&](int cur, int kt, int qc, int q0w, const bf16x8& qf0,
                  const bf16x8& qf1, f32x4 (&acc)[4], float& m_, float& l_) {
    const char* Kt = smem + cur * 8192;
    const char* Vv = smem + 16384 + cur * 8192;
    const int kbase = kt * 64;

    bf16x8 kf[4][2];
#pragma unroll
    for (int bb = 0; bb < 4; ++bb) {
      int rr = 16 * bb + qi;
      kf[bb][0] = *(const bf16x8*)(Kt + rr * 128 + ((g ^ (rr & 7)) << 4));
      kf[bb][1] = *(const bf16x8*)(Kt + rr * 128 + (((g + 4) ^ (rr & 7)) << 4));
    }

    f32x4 st[4];
    __builtin_amdgcn_s_setprio(1);
#pragma unroll
    for (int bb = 0; bb < 4; ++bb) {
      st[bb] = mfma16(kf[bb][0], qf0, (f32x4){0.f, 0.f, 0.f, 0.f});
      st[bb] = mfma16(kf[bb][1], qf1, st[bb]);
    }
    __builtin_amdgcn_s_setprio(0);

    bf16x8 vf[4][2];
#pragma unroll
    for (int j = 0; j < 4; ++j) {
      int rr = 16 * j + qi;
      vf[j][0] = *(const bf16x8*)(Vv + rr * 128 + ((g ^ (rr & 7)) << 4));
      vf[j][1] = *(const bf16x8*)(Vv + rr * 128 + (((g + 4) ^ (rr & 7)) << 4));
    }

    // mask (diagonal tile only) + tree max; scores in log2 domain (Q folded)
    if (kt == qc) {
#pragma unroll
      for (int bb = 0; bb < 4; ++bb)
#pragma unroll
        for (int r = 0; r < 4; ++r)
          if (kbase + 16 * bb + 4 * g + r > q0w + qi) st[bb][r] = -1e30f;
    }
    float mb4[4];
#pragma unroll
    for (int bb = 0; bb < 4; ++bb)
      mb4[bb] = fmaxf(fmaxf(st[bb][0], st[bb][1]), fmaxf(st[bb][2], st[bb][3]));
    float tmax = fmaxf(fmaxf(mb4[0], mb4[1]), fmaxf(mb4[2], mb4[3]));
    tmax = fmaxf(tmax, __shfl_xor(tmax, 16));
    tmax = fmaxf(tmax, __shfl_xor(tmax, 32));

    // deferred-max: rescale only when the running max grew by > 7 (log2)
    if (!__all(tmax <= m_ + 7.0f)) {
      const float mnew = fmaxf(m_, tmax);
      const float corr = exp2f(m_ - mnew);
      l_ *= corr;
      float cr[4];
#pragma unroll
      for (int r = 0; r < 4; ++r) cr[r] = __shfl(corr, 4 * g + r);
#pragma unroll
      for (int j = 0; j < 4; ++j) {
        acc[j][0] *= cr[0]; acc[j][1] *= cr[1];
        acc[j][2] *= cr[2]; acc[j][3] *= cr[3];
      }
      m_ = mnew;
    }

    float lsb[4];
#pragma unroll
    for (int bb = 0; bb < 4; ++bb) {
      float p0 = exp2f(st[bb][0] - m_), p1 = exp2f(st[bb][1] - m_);
      float p2 = exp2f(st[bb][2] - m_), p3 = exp2f(st[bb][3] - m_);
      lsb[bb] = (p0 + p1) + (p2 + p3);
      bf16x2 w0 = {(__bf16)p0, (__bf16)p1};
      bf16x2 w1 = {(__bf16)p2, (__bf16)p3};
      *(uint2*)(myP + qi * 128 + ((32 * bb + 8 * g) ^ swz)) =
          make_uint2(__builtin_bit_cast(unsigned int, w0),
                     __builtin_bit_cast(unsigned int, w1));
    }
    float ls = (lsb[0] + lsb[1]) + (lsb[2] + lsb[3]);
    ls += __shfl_xor(ls, 16);
    ls += __shfl_xor(ls, 32);
    l_ += ls;

    bf16x8 pa0 = *(bf16x8*)(myP + qi * 128 + ((16 * g) ^ swz));
    bf16x8 pa1 = *(bf16x8*)(myP + qi * 128 + ((64 + 16 * g) ^ swz));
    __builtin_amdgcn_s_setprio(1);
#pragma unroll
    for (int j = 0; j < 4; ++j) {
      acc[j] = mfma16(pa0, vf[j][0], acc[j]);
      acc[j] = mfma16(pa1, vf[j][1], acc[j]);
    }
    __builtin_amdgcn_s_setprio(0);
  };

  auto run_chunk = [&](int qc) {
    const int q0w = qc * 64 + rg * 16;
    const int nt = qc + 1;

    const bf16x8 qf0 = *(const bf16x8*)(Qp + (q0w + qi) * DK + 8 * g);
    const bf16x8 qf1 = *(const bf16x8*)(Qp + (q0w + qi) * DK + 32 + 8 * g);

    f32x4 acc[4];
#pragma unroll
    for (int j = 0; j < 4; ++j) acc[j] = (f32x4){0.f, 0.f, 0.f, 0.f};
    float m_ = -1e30f, l_ = 0.f;

    __syncthreads();  // protect buffers from previous chunk's readers
    stage(0, 0);

    int cur = 0;
    for (int kt = 0; kt < nt; ++kt) {
      __syncthreads();  // buf[cur] staged (drains vmcnt on all waves)
      if (kt + 1 < nt) stage(cur ^ 1, kt + 1);
      if ((kt & 1) == par)
        tile(cur, kt, qc, q0w, qf0, qf1, acc, m_, l_);
      cur ^= 1;
    }

    // ---- exact merge of the two parity states (through free K/V LDS) ----
    __syncthreads();  // all tiles done; K/V buffers free
    char* Mb = smem + rg * 8192 + lane * 80;
    if (par == 1) {
      *(f32x4*)(Mb + 0)  = acc[0];
      *(f32x4*)(Mb + 16) = acc[1];
      *(f32x4*)(Mb + 32) = acc[2];
      *(f32x4*)(Mb + 48) = acc[3];
      *(float*)(Mb + 64) = m_;
      *(float*)(Mb + 68) = l_;
    }
    __syncthreads();
    if (par == 0) {
      f32x4 a1[4];
      a1[0] = *(const f32x4*)(Mb + 0);
      a1[1] = *(const f32x4*)(Mb + 16);
      a1[2] = *(const f32x4*)(Mb + 32);
      a1[3] = *(const f32x4*)(Mb + 48);
      float m1 = *(const float*)(Mb + 64);
      float l1 = *(const float*)(Mb + 68);
      const float mn = fmaxf(m_, m1);
      const float c0 = exp2f(m_ - mn), c1 = exp2f(m1 - mn);
      const float lt = l_ * c0 + l1 * c1;
      float cr0[4], cr1[4];
#pragma unroll
      for (int r = 0; r < 4; ++r) {
        cr0[r] = __shfl(c0, 4 * g + r);
        cr1[r] = __shfl(c1, 4 * g + r);
      }
#pragma unroll
      for (int j = 0; j < 4; ++j)
#pragma unroll
        for (int r = 0; r < 4; ++r)
          acc[j][r] = acc[j][r] * cr0[r] + a1[j][r] * cr1[r];

      const float inv = 1.f / lt;
      float ir[4];
#pragma unroll
      for (int r = 0; r < 4; ++r) ir[r] = __shfl(inv, 4 * g + r);
#pragma unroll
      for (int j = 0; j < 4; ++j)
#pragma unroll
        for (int r = 0; r < 4; ++r)
          AOs[((size_t)b * Sq + q0w + 4 * g + r) * Dm + h * DK + 16 * j + qi] =
              bfb(acc[j][r] * ir[r]);
    }
  };

  run_chunk(31 - pair);  // big chunk first
  run_chunk(pair);
}

// ================================ launch ===================================
extern "C" void kernel_launch(void* const* d_in, const int* in_sizes, int n_in,
                              void* d_out, int out_size, void* d_ws,
                              size_t ws_size, hipStream_t stream) {
  const float* x  = (const float*)d_in[0];
  const float* Wq = (const float*)d_in[1];
  const float* Wk = (const float*)d_in[2];
  const float* Wv = (const float*)d_in[3];
  const float* Wo = (const float*)d_in[4];
  float* out = (float*)d_out;

  char* w = (char*)d_ws;
  __bf16* Qb  = (__bf16*)(w);                 // 8 MB [bh][s][64] (pre-scaled)
  __bf16* Kb  = (__bf16*)(w + (8u << 20));    // 8 MB
  __bf16* Vt  = (__bf16*)(w + (16u << 20));   // 8 MB [bh][64][s]
  __bf16* AOb = (__bf16*)(w + (24u << 20));   // 8 MB [B,S,D]
  __bf16* xb  = (__bf16*)(w + (32u << 20));   // 8 MB [4096][1024]
  __bf16* Wt  = (__bf16*)(w + (40u << 20));   // 4 x 2 MB [n][k]
  float2* tbl = (float2*)(w + (48u << 20));   // 512 KB

  prep_kernel<<<6400, 256, 0, stream>>>(x, Wq, Wk, Wv, Wo, xb, Wt, tbl);
  gemm_qkv<<<768, 256, 0, stream>>>(xb, Wt, tbl, Qb, Kb, Vt);
  attn_kernel<<<512, 512, 0, stream>>>(Qb, Kb, Vt, AOb);
  gemm_o<<<256, 256, 0, stream>>>(AOb, Wt + (size_t)3 * Dm * Dm, out);
}

// Round 11
// 126.761 us; speedup vs baseline: 1.1171x; 1.0059x over previous
//
#include <hip/hip_runtime.h>
#include <cmath>

// ---------------------------------------------------------------------------
// MHA forward, bf16-MFMA everywhere.
//   prep (1 kernel): x->bf16 ; W* -> bf16 transposed [n][k] ; RoPE table
//   gemm_qkv (768 blk, XCD m-band swizzled): xb@Wt -> Q/K (RoPE via LDS
//       transpose epilogue, coalesced) / V-transpose epilogue
//   attn: causal flash attn, 8-wave blocks; 128-k staged tile per barrier
//         interval, k-parity waves compute the two 64-k halves concurrently
//         (exact softmax-state merge at chunk end); paired q-chunks
//         (uniform 17 intervals); XCD-partitioned; deferred-max log2 softmax
//   gemm_o (256 blk, swizzled): AOb@Wto -> out fp32 (LDS fp32 2-pass epilogue)
// B=2 S=2048 D=1024 H=16 dk=64
// ---------------------------------------------------------------------------

constexpr int Bz = 2, Sq = 2048, Dm = 1024, Hh = 16, DK = 64;
constexpr int Mrows = Bz * Sq;  // 4096

typedef __attribute__((ext_vector_type(4))) float f32x4;
typedef __attribute__((ext_vector_type(2))) __bf16 bf16x2;
typedef __attribute__((ext_vector_type(4))) __bf16 bf16x4;
typedef __attribute__((ext_vector_type(8))) __bf16 bf16x8;
typedef __attribute__((ext_vector_type(8))) short short8v;

__device__ __forceinline__ f32x4 mfma16(bf16x8 a, bf16x8 b, f32x4 c) {
  return __builtin_amdgcn_mfma_f32_16x16x32_bf16(a, b, c, 0, 0, 0);
}
__device__ __forceinline__ short bfb(float x) {
  return __builtin_bit_cast(short, (__bf16)x);
}
// async global->LDS, 16 B per lane; lds ptr must be wave-uniform
__device__ __forceinline__ void gload16(const void* g, void* l) {
  __builtin_amdgcn_global_load_lds(
      (__attribute__((address_space(1))) void*)g,
      (__attribute__((address_space(3))) void*)l, 16, 0, 0);
}

// ============================ prep (fused) =================================
// blocks [0,2048): x->bf16 ; [2048,6144): W transpose ; [6144,6400): RoPE tbl
__global__ __launch_bounds__(256) void prep_kernel(
    const float* __restrict__ x, const float* __restrict__ Wq,
    const float* __restrict__ Wk, const float* __restrict__ Wv,
    const float* __restrict__ Wo, __bf16* __restrict__ xb,
    __bf16* __restrict__ Wt, float2* __restrict__ tbl) {
  __shared__ float tile[32][33];
  const int bid = blockIdx.x, tid = threadIdx.x;
  if (bid < 2048) {
    int t = bid * 256 + tid;
    const float4* p = (const float4*)x + (size_t)t * 2;
    float4 a = p[0], b = p[1];
    bf16x8 o = {(__bf16)a.x, (__bf16)a.y, (__bf16)a.z, (__bf16)a.w,
                (__bf16)b.x, (__bf16)b.y, (__bf16)b.z, (__bf16)b.w};
    *(bf16x8*)(xb + (size_t)t * 8) = o;
  } else if (bid < 6144) {
    int wid = bid - 2048;
    int z = wid >> 10, rem = wid & 1023;
    const float* W = (z == 0) ? Wq : (z == 1) ? Wk : (z == 2) ? Wv : Wo;
    __bf16* out = Wt + (size_t)z * Dm * Dm;
    int r0 = (rem >> 5) * 32, c0 = (rem & 31) * 32;
    int r = tid >> 3, c4 = (tid & 7) * 4;
    float4 v = *(const float4*)&W[(size_t)(r0 + r) * Dm + c0 + c4];
    tile[r][c4] = v.x; tile[r][c4 + 1] = v.y;
    tile[r][c4 + 2] = v.z; tile[r][c4 + 3] = v.w;
    __syncthreads();
    int nl = tid >> 3, k4 = (tid & 7) * 4;
    bf16x4 o = {(__bf16)tile[k4][nl], (__bf16)tile[k4 + 1][nl],
                (__bf16)tile[k4 + 2][nl], (__bf16)tile[k4 + 3][nl]};
    *(bf16x4*)&out[(size_t)(c0 + nl) * Dm + r0 + k4] = o;
  } else {
    int t = (bid - 6144) * 256 + tid;  // 65536
    int s = t >> 5, j = t & 31;
    float inv = exp2f(-13.287712379549449f * (1.0f / 32.0f) * (float)j);
    float sn, cs;
    sincosf((float)s * inv, &sn, &cs);
    tbl[t] = make_float2(cs, sn);
  }
}

// ========================= bf16 MFMA GEMM core =============================
// acc[4][4] = A[m0..+128][:] @ Bt[n0..+128][:]^T, BK=32, 4 waves, 16x16x32.
__device__ __forceinline__ void gemm_core(const __bf16* __restrict__ A,
                                          const __bf16* __restrict__ Bt,
                                          char* smem, f32x4 (&acc)[4][4],
                                          int m0, int n0, int tid) {
  short* As = (short*)smem;            // [128][32]
  short* Bs = (short*)(smem + 8192);   // [128][32]
  const int lane = tid & 63, w = tid >> 6;
  const int qi = lane & 15, c = lane >> 4;
  const int wr = w >> 1, wc = w & 1;
  const int srow = lane >> 2, scol = (lane & 3) * 8;
  const __bf16* gA = A + (size_t)(m0 + w * 16 + srow) * Dm + scol;
  const __bf16* gB = Bt + (size_t)(n0 + w * 16 + srow) * Dm + scol;
  short* lA = As + w * 512;  // wave-uniform LDS dest
  short* lB = Bs + w * 512;

#pragma unroll
  for (int i = 0; i < 4; ++i)
#pragma unroll
    for (int j = 0; j < 4; ++j) acc[i][j] = (f32x4){0.f, 0.f, 0.f, 0.f};

  for (int k0 = 0; k0 < Dm; k0 += 32) {
    if (k0) __syncthreads();
    gload16(gA + k0, lA);
    gload16(gA + (size_t)64 * Dm + k0, lA + 2048);
    gload16(gB + k0, lB);
    gload16(gB + (size_t)64 * Dm + k0, lB + 2048);
    __syncthreads();
    bf16x8 af[4], bfv[4];
#pragma unroll
    for (int i = 0; i < 4; ++i) {
      af[i]  = *(bf16x8*)(As + (wr * 64 + i * 16 + qi) * 32 + c * 8);
      bfv[i] = *(bf16x8*)(Bs + (wc * 64 + i * 16 + qi) * 32 + c * 8);
    }
#pragma unroll
    for (int i = 0; i < 4; ++i)
#pragma unroll
      for (int j = 0; j < 4; ++j) acc[i][j] = mfma16(af[i], bfv[j], acc[i][j]);
  }
}

// ===================== fused QKV GEMM (flattened grid) =====================
// 768 blocks. XCD m-band swizzle: xcd=bid&7 owns m-blocks 4*xcd..+3; within
// XCD order is m-inner so B tiles get back-to-back L2 reuse.
// z==0: Q + RoPE (scaled 0.125*log2e). z==1: K + RoPE. z==2: Vt[bh][d][s].
__global__ __launch_bounds__(256) void gemm_qkv(
    const __bf16* __restrict__ xb, const __bf16* __restrict__ Wt,
    const float2* __restrict__ tbl, __bf16* __restrict__ Qb,
    __bf16* __restrict__ Kb, __bf16* __restrict__ Vt) {
  __shared__ __align__(16) char smem[34816];
  const int tid = threadIdx.x;
  const int bid = blockIdx.x;
  const int xcd = bid & 7, r8 = bid >> 3;          // r8 in [0,96)
  const int mb = (xcd << 2) | (r8 & 3);            // m-block 0..31
  const int zn = r8 >> 2;                          // 0..23
  const int z = zn >> 3, nb = zn & 7;
  const int m0 = mb * 128, n0 = nb * 128;

  f32x4 acc[4][4];
  gemm_core(xb, Wt + (size_t)z * Dm * Dm, smem, acc, m0, n0, tid);

  const int lane = tid & 63, w = tid >> 6;
  const int qi = lane & 15, c = lane >> 4;
  const int wr = w >> 1, wc = w & 1;

  if (z == 2) {  // Vt[bh][d][s]
    __syncthreads();
    short* T = (short*)smem;  // [128][136] padded
#pragma unroll
    for (int i = 0; i < 4; ++i)
#pragma unroll
      for (int j = 0; j < 4; ++j) {
        int nl = wc * 64 + j * 16 + qi;
        int mbr = wr * 64 + i * 16 + c * 4;
        bf16x4 pk = {(__bf16)acc[i][j][0], (__bf16)acc[i][j][1],
                     (__bf16)acc[i][j][2], (__bf16)acc[i][j][3]};
        *(bf16x4*)(T + nl * 136 + mbr) = pk;
      }
    __syncthreads();
    short* C = (short*)Vt;
    int b = m0 >> 11, sb = m0 & (Sq - 1);
#pragma unroll
    for (int it = 0; it < 8; ++it) {
      int f = tid + it * 256;
      int nl = f >> 4, mc = f & 15;
      short8v v = *(short8v*)(T + nl * 136 + mc * 8);
      int ng = n0 + nl;
      int d = ng & (DK - 1), h = (ng >> 6) & (Hh - 1);
      *(short8v*)(C + ((size_t)(b * Hh + h) * DK + d) * Sq + sb + mc * 8) = v;
    }
  } else {  // Q or K: stage raw bf16, RoPE on re-read (pairs in-thread)
    __syncthreads();
    short* T = (short*)smem;  // [128][136]
#pragma unroll
    for (int i = 0; i < 4; ++i)
#pragma unroll
      for (int j = 0; j < 4; ++j) {
        int nl = wc * 64 + j * 16 + qi;
        int mbr = wr * 64 + i * 16 + c * 4;
#pragma unroll
        for (int rr = 0; rr < 4; ++rr)
          T[(mbr + rr) * 136 + nl] = bfb(acc[i][j][rr]);
      }
    __syncthreads();
    const float sc = (z == 0) ? 0.18033688011112042f : 1.0f;  // 0.125*log2e
    short* C = (short*)((z == 0) ? Qb : Kb);
    const int b = m0 >> 11;
#pragma unroll
    for (int it = 0; it < 8; ++it) {
      int f = tid + it * 256;
      int ml = f >> 4, c16 = f & 15;
      bf16x8 v = *(bf16x8*)(T + ml * 136 + c16 * 8);
      int s = (m0 + ml) & (Sq - 1);
      int n = n0 + c16 * 8;
      int d0 = n & (DK - 1), h = (n >> 6) & (Hh - 1);
      int jj = d0 >> 1;
      float4 t01 = *(const float4*)&tbl[s * 32 + jj];      // cos0,sin0,cos1,sin1
      float4 t23 = *(const float4*)&tbl[s * 32 + jj + 2];
      bf16x8 o;
      float x0 = (float)v[0], y0 = (float)v[1];
      o[0] = (__bf16)((x0 * t01.x - y0 * t01.y) * sc);
      o[1] = (__bf16)((y0 * t01.x + x0 * t01.y) * sc);
      float x1 = (float)v[2], y1 = (float)v[3];
      o[2] = (__bf16)((x1 * t01.z - y1 * t01.w) * sc);
      o[3] = (__bf16)((y1 * t01.z + x1 * t01.w) * sc);
      float x2 = (float)v[4], y2 = (float)v[5];
      o[4] = (__bf16)((x2 * t23.x - y2 * t23.y) * sc);
      o[5] = (__bf16)((y2 * t23.x + x2 * t23.y) * sc);
      float x3 = (float)v[6], y3 = (float)v[7];
      o[6] = (__bf16)((x3 * t23.z - y3 * t23.w) * sc);
      o[7] = (__bf16)((y3 * t23.z + x3 * t23.w) * sc);
      *(bf16x8*)(C + ((size_t)(b * Hh + h) * Sq + s) * DK + d0) = o;
    }
  }
}

// ============================== O GEMM =====================================
// 256 blocks, XCD m-band swizzle. fp32 output via 2-pass LDS transpose.
__global__ __launch_bounds__(256) void gemm_o(
    const __bf16* __restrict__ AOb, const __bf16* __restrict__ Wto,
    float* __restrict__ C) {
  __shared__ __align__(16) char smem[34816];
  const int tid = threadIdx.x;
  const int bid = blockIdx.x;
  const int xcd = bid & 7, r8 = bid >> 3;          // r8 in [0,32)
  const int mb = (xcd << 2) | (r8 & 3);
  const int nb = r8 >> 2;
  const int m0 = mb * 128, n0 = nb * 128;

  f32x4 acc[4][4];
  gemm_core(AOb, Wto, smem, acc, m0, n0, tid);

  const int lane = tid & 63, w = tid >> 6;
  const int qi = lane & 15, c = lane >> 4;
  const int wr = w >> 1, wc = w & 1;
  float* T32 = (float*)smem;  // [64][132] = 33792 B

#pragma unroll
  for (int pass = 0; pass < 2; ++pass) {
    __syncthreads();
#pragma unroll
    for (int i2 = 0; i2 < 2; ++i2) {
      int i = pass * 2 + i2;
#pragma unroll
      for (int j = 0; j < 4; ++j) {
        int nl = wc * 64 + j * 16 + qi;
        int cm = wr * 32 + i2 * 16 + c * 4;
#pragma unroll
        for (int rr = 0; rr < 4; ++rr)
          T32[(cm + rr) * 132 + nl] = acc[i][j][rr];
      }
    }
    __syncthreads();
#pragma unroll
    for (int it = 0; it < 8; ++it) {
      int f = tid + it * 256;           // 0..2047
      int cm = f >> 5, c4 = f & 31;
      float4 v = *(float4*)(T32 + cm * 132 + c4 * 4);
      int m = m0 + (cm >> 5) * 64 + pass * 32 + (cm & 31);
      *(float4*)&C[(size_t)m * Dm + n0 + c4 * 4] = v;
    }
  }
}

// ======================= Flash attention (bf16 MFMA) ========================
// 512 blocks x 8 waves (512 thr). wave -> (rg = row-group 0..3, par = k-half).
// Per barrier interval: stage K[128][64]+V[64][128] (32 KB); par0 computes
// k-half [0,64), par1 [64,128) CONCURRENTLY (virtual 64-tile ktv = 2t+par,
// compute iff ktv<=qc, mask iff ktv==qc). Exact softmax-state merge at chunk
// end. Paired q-chunks -> uniform 17 intervals/block. XCD-partitioned.
// LDS (dynamic 80 KB): K[2][16K]@0, V[2][16K]@32K, P[8][2K]@64K.
__global__ __launch_bounds__(512, 4) void attn_kernel(
    const __bf16* __restrict__ Qb, const __bf16* __restrict__ Kb,
    const __bf16* __restrict__ Vt, __bf16* __restrict__ AOb) {
  extern __shared__ __align__(16) char smem[];

  const int bid = blockIdx.x;            // 512
  const int xcd = bid & 7;               // hw round-robin -> XCD id (heuristic)
  const int idx = bid >> 3;              // 0..63 within XCD
  const int bh = (xcd << 2) | (idx >> 4);
  const int pair = idx & 15;             // chunks: 31-pair then pair
  const int b = bh >> 4, h = bh & (Hh - 1);
  const int tid = threadIdx.x, lane = tid & 63, w = tid >> 6;  // w 0..7
  const int rg = w & 3, par = w >> 2;
  const int g = lane >> 4, qi = lane & 15;

  const __bf16* Qp = Qb + (size_t)bh * Sq * DK;
  const __bf16* Kp = Kb + (size_t)bh * Sq * DK;
  const __bf16* Vp = Vt + (size_t)bh * DK * Sq;

  char* myP = smem + 65536 + w * 2048;
  const int swz = (qi & 7) << 4;
  const int srow8 = lane >> 3, scol8 = lane & 7;    // K: 8 rows/seg (128B rows)
  const int srow4 = lane >> 4, scol16 = lane & 15;  // V: 4 rows/seg (256B rows)
  short* AOs = (short*)AOb;

  // stage K[128 rows][64] + V[64 rows][128 cols] of 128-k tile t into buf cb.
  // Sources pre-swizzled so linear LDS + swizzled reads are conflict-free.
  auto stage = [&](int cb, int t) {
    const int kbase = t * 128;
    char* Kd = smem + cb * 16384;
    char* Vd = smem + 32768 + cb * 16384;
#pragma unroll
    for (int s2 = 0; s2 < 2; ++s2) {
      int seg = w * 2 + s2;
      int r = seg * 8 + srow8;                       // K row 0..127
      gload16(Kp + (size_t)(kbase + r) * DK + ((scol8 ^ (r & 7)) << 3),
              Kd + seg * 1024);
      int d = seg * 4 + srow4;                       // V row 0..63
      int ss = (scol16 & 8) | ((scol16 ^ (d & 7)) & 7);  // keep k-half bit
      gload16(Vp + (size_t)d * Sq + kbase + ss * 8, Vd + seg * 1024);
    }
  };

  // one 64-k virtual tile (parity half of the staged 128-k tile)
  auto tile = [&](int cb, int ktv, int qc, int q0w, const bf16x8& qf0,
                  const bf16x8& qf1, f32x4 (&acc)[4], float& m_, float& l_) {
    const char* Kt = smem + cb * 16384 + par * 8192;
    const char* Vv = smem + 32768 + cb * 16384;
    const int vpo = par * 128;         // byte offset of this k-half in V rows
    const int kbase = ktv * 64;

    bf16x8 kf[4][2];
#pragma unroll
    for (int bb = 0; bb < 4; ++bb) {
      int rr = 16 * bb + qi;
      kf[bb][0] = *(const bf16x8*)(Kt + rr * 128 + ((g ^ (rr & 7)) << 4));
      kf[bb][1] = *(const bf16x8*)(Kt + rr * 128 + (((g + 4) ^ (rr & 7)) << 4));
    }

    f32x4 st[4];
    __builtin_amdgcn_s_setprio(1);
#pragma unroll
    for (int bb = 0; bb < 4; ++bb) {
      st[bb] = mfma16(kf[bb][0], qf0, (f32x4){0.f, 0.f, 0.f, 0.f});
      st[bb] = mfma16(kf[bb][1], qf1, st[bb]);
    }
    __builtin_amdgcn_s_setprio(0);

    bf16x8 vf[4][2];
#pragma unroll
    for (int j = 0; j < 4; ++j) {
      int rr = 16 * j + qi;
      vf[j][0] = *(const bf16x8*)(Vv + rr * 256 + vpo + ((g ^ (rr & 7)) << 4));
      vf[j][1] =
          *(const bf16x8*)(Vv + rr * 256 + vpo + (((g + 4) ^ (rr & 7)) << 4));
    }

    // mask (diagonal virtual tile only); scores in log2 domain (Q folded)
    if (ktv == qc) {
#pragma unroll
      for (int bb = 0; bb < 4; ++bb)
#pragma unroll
        for (int r = 0; r < 4; ++r)
          if (kbase + 16 * bb + 4 * g + r > q0w + qi) st[bb][r] = -1e30f;
    }
    float mb4[4];
#pragma unroll
    for (int bb = 0; bb < 4; ++bb)
      mb4[bb] = fmaxf(fmaxf(st[bb][0], st[bb][1]), fmaxf(st[bb][2], st[bb][3]));
    float tmax = fmaxf(fmaxf(mb4[0], mb4[1]), fmaxf(mb4[2], mb4[3]));
    tmax = fmaxf(tmax, __shfl_xor(tmax, 16));
    tmax = fmaxf(tmax, __shfl_xor(tmax, 32));

    // deferred-max: rescale only when the running max grew by > 7 (log2)
    if (!__all(tmax <= m_ + 7.0f)) {
      const float mnew = fmaxf(m_, tmax);
      const float corr = exp2f(m_ - mnew);
      l_ *= corr;
      float cr[4];
#pragma unroll
      for (int r = 0; r < 4; ++r) cr[r] = __shfl(corr, 4 * g + r);
#pragma unroll
      for (int j = 0; j < 4; ++j) {
        acc[j][0] *= cr[0]; acc[j][1] *= cr[1];
        acc[j][2] *= cr[2]; acc[j][3] *= cr[3];
      }
      m_ = mnew;
    }

    float lsb[4];
#pragma unroll
    for (int bb = 0; bb < 4; ++bb) {
      float p0 = exp2f(st[bb][0] - m_), p1 = exp2f(st[bb][1] - m_);
      float p2 = exp2f(st[bb][2] - m_), p3 = exp2f(st[bb][3] - m_);
      lsb[bb] = (p0 + p1) + (p2 + p3);
      bf16x2 w0 = {(__bf16)p0, (__bf16)p1};
      bf16x2 w1 = {(__bf16)p2, (__bf16)p3};
      *(uint2*)(myP + qi * 128 + ((32 * bb + 8 * g) ^ swz)) =
          make_uint2(__builtin_bit_cast(unsigned int, w0),
                     __builtin_bit_cast(unsigned int, w1));
    }
    float ls = (lsb[0] + lsb[1]) + (lsb[2] + lsb[3]);
    ls += __shfl_xor(ls, 16);
    ls += __shfl_xor(ls, 32);
    l_ += ls;

    bf16x8 pa0 = *(bf16x8*)(myP + qi * 128 + ((16 * g) ^ swz));
    bf16x8 pa1 = *(bf16x8*)(myP + qi * 128 + ((64 + 16 * g) ^ swz));
    __builtin_amdgcn_s_setprio(1);
#pragma unroll
    for (int j = 0; j < 4; ++j) {
      acc[j] = mfma16(pa0, vf[j][0], acc[j]);
      acc[j] = mfma16(pa1, vf[j][1], acc[j]);
    }
    __builtin_amdgcn_s_setprio(0);
  };

  auto run_chunk = [&](int qc) {
    const int q0w = qc * 64 + rg * 16;
    const int nt = (qc >> 1) + 1;  // 128-k tiles

    const bf16x8 qf0 = *(const bf16x8*)(Qp + (q0w + qi) * DK + 8 * g);
    const bf16x8 qf1 = *(const bf16x8*)(Qp + (q0w + qi) * DK + 32 + 8 * g);

    f32x4 acc[4];
#pragma unroll
    for (int j = 0; j < 4; ++j) acc[j] = (f32x4){0.f, 0.f, 0.f, 0.f};
    float m_ = -1e30f, l_ = 0.f;

    __syncthreads();  // protect buffers from previous chunk's readers
    stage(0, 0);

    int cur = 0;
    for (int t = 0; t < nt; ++t) {
      __syncthreads();  // buf[cur] staged (drains vmcnt on all waves)
      if (t + 1 < nt) stage(cur ^ 1, t + 1);
      int ktv = 2 * t + par;
      if (ktv <= qc)
        tile(cur, ktv, qc, q0w, qf0, qf1, acc, m_, l_);
      cur ^= 1;
    }

    // ---- exact merge of the two parity states (through free K LDS) ----
    __syncthreads();  // all tiles done; K/V buffers free
    char* Mb = smem + rg * 8192 + lane * 80;
    if (par == 1) {
      *(f32x4*)(Mb + 0)  = acc[0];
      *(f32x4*)(Mb + 16) = acc[1];
      *(f32x4*)(Mb + 32) = acc[2];
      *(f32x4*)(Mb + 48) = acc[3];
      *(float*)(Mb + 64) = m_;
      *(float*)(Mb + 68) = l_;
    }
    __syncthreads();
    if (par == 0) {
      f32x4 a1[4];
      a1[0] = *(const f32x4*)(Mb + 0);
      a1[1] = *(const f32x4*)(Mb + 16);
      a1[2] = *(const f32x4*)(Mb + 32);
      a1[3] = *(const f32x4*)(Mb + 48);
      float m1 = *(const float*)(Mb + 64);
      float l1 = *(const float*)(Mb + 68);
      const float mn = fmaxf(m_, m1);
      const float c0 = exp2f(m_ - mn), c1 = exp2f(m1 - mn);
      const float lt = l_ * c0 + l1 * c1;
      float cr0[4], cr1[4];
#pragma unroll
      for (int r = 0; r < 4; ++r) {
        cr0[r] = __shfl(c0, 4 * g + r);
        cr1[r] = __shfl(c1, 4 * g + r);
      }
#pragma unroll
      for (int j = 0; j < 4; ++j)
#pragma unroll
        for (int r = 0; r < 4; ++r)
          acc[j][r] = acc[j][r] * cr0[r] + a1[j][r] * cr1[r];

      const float inv = 1.f / lt;
      float ir[4];
#pragma unroll
      for (int r = 0; r < 4; ++r) ir[r] = __shfl(inv, 4 * g + r);
#pragma unroll
      for (int j = 0; j < 4; ++j)
#pragma unroll
        for (int r = 0; r < 4; ++r)
          AOs[((size_t)b * Sq + q0w + 4 * g + r) * Dm + h * DK + 16 * j + qi] =
              bfb(acc[j][r] * ir[r]);
    }
  };

  run_chunk(31 - pair);  // big chunk first
  run_chunk(pair);
}

// ================================ launch ===================================
extern "C" void kernel_launch(void* const* d_in, const int* in_sizes, int n_in,
                              void* d_out, int out_size, void* d_ws,
                              size_t ws_size, hipStream_t stream) {
  const float* x  = (const float*)d_in[0];
  const float* Wq = (const float*)d_in[1];
  const float* Wk = (const float*)d_in[2];
  const float* Wv = (const float*)d_in[3];
  const float* Wo = (const float*)d_in[4];
  float* out = (float*)d_out;

  char* w = (char*)d_ws;
  __bf16* Qb  = (__bf16*)(w);                 // 8 MB [bh][s][64] (pre-scaled)
  __bf16* Kb  = (__bf16*)(w + (8u << 20));    // 8 MB
  __bf16* Vt  = (__bf16*)(w + (16u << 20));   // 8 MB [bh][64][s]
  __bf16* AOb = (__bf16*)(w + (24u << 20));   // 8 MB [B,S,D]
  __bf16* xb  = (__bf16*)(w + (32u << 20));   // 8 MB [4096][1024]
  __bf16* Wt  = (__bf16*)(w + (40u << 20));   // 4 x 2 MB [n][k]
  float2* tbl = (float2*)(w + (48u << 20));   // 512 KB

  prep_kernel<<<6400, 256, 0, stream>>>(x, Wq, Wk, Wv, Wo, xb, Wt, tbl);
  gemm_qkv<<<768, 256, 0, stream>>>(xb, Wt, tbl, Qb, Kb, Vt);
  attn_kernel<<<512, 512, 81920, stream>>>(Qb, Kb, Vt, AOb);
  gemm_o<<<256, 256, 0, stream>>>(AOb, Wt + (size_t)3 * Dm * Dm, out);
}